// Round 5
// baseline (749.026 us; speedup 1.0000x reference)
//
#include <hip/hip_runtime.h>

// Segment mean: x [N, D=128] fp32, B=16 contiguous segments (lengths[16]).
// out [16,128] fp32 = per-segment column means.
//
// v4-DIAG: identical to v3c except phase 1 reads x TWICE (two accumulation
// passes; finish divides by 2*len). Purpose: phase 1's true duration and
// counters (hbm_gbps, FETCH_SIZE, VALUBusy, Occupancy) become visible in the
// top-5 dispatch table, breaking the fill-vs-kernel accounting degeneracy.
// dur_us is expected to REGRESS by exactly one phase-1 pass; revert next round.

#define SEG_D   128
#define SEG_D4  32    // 128 floats = 32 float4
#define NSEG    16
#define CROWS   512   // rows per chunk; chunk = 256 KiB

__device__ __forceinline__ void acc4(float4& a, const float4 v) {
  a.x += v.x; a.y += v.y; a.z += v.z; a.w += v.w;
}

__global__ __launch_bounds__(256) void seg_partial_kernel(
    const float4* __restrict__ x4,
    const int* __restrict__ lengths,
    float4* __restrict__ partial,   // [T][2][SEG_D4]
    int nrows) {
  const int b = blockIdx.x;
  const int t = threadIdx.x;
  const long long row_lo = (long long)b * CROWS;
  long long row_hi = row_lo + CROWS;
  if (row_hi > nrows) row_hi = nrows;

  // Find end row of the segment containing row_lo.
  long long pre = 0, endA = 0;
  for (int i = 0; i < NSEG; ++i) {
    const long long l = lengths[i];
    if (pre + l > row_lo) { endA = pre + l; break; }
    pre += l;
  }
  const long long split = endA < row_hi ? endA : row_hi;

  const float4* __restrict__ base = x4 + row_lo * SEG_D4;
  const int nf  = (int)((row_hi - row_lo) * SEG_D4);   // <= CROWS*32 = 16384
  const int sp4 = (int)((split - row_lo) * SEG_D4);

  float4 a0 = make_float4(0.f, 0.f, 0.f, 0.f);
  float4 a1 = a0, a2 = a0, a3 = a0;           // run A accumulators
  float4 b0 = a0, b1 = a0, b2 = a0, b3 = a0;  // run B accumulators

  // DIAG: two full passes over this block's chunk. Accumulators carry across
  // passes; finish kernel divides by 2*len.
  for (int pass = 0; pass < 2; ++pass) {
    int i = t;
    for (; i + 768 < nf; i += 1024) {
      const float4 v0 = base[i];
      const float4 v1 = base[i + 256];
      const float4 v2 = base[i + 512];
      const float4 v3 = base[i + 768];
      if (i       < sp4) acc4(a0, v0); else acc4(b0, v0);
      if (i + 256 < sp4) acc4(a1, v1); else acc4(b1, v1);
      if (i + 512 < sp4) acc4(a2, v2); else acc4(b2, v2);
      if (i + 768 < sp4) acc4(a3, v3); else acc4(b3, v3);
    }
    for (; i < nf; i += 256) {
      const float4 v = base[i];
      if (i < sp4) acc4(a0, v); else acc4(b0, v);
    }
  }
  acc4(a0, a1); acc4(a2, a3); acc4(a0, a2);
  acc4(b0, b1); acc4(b2, b3); acc4(b0, b2);

  // Reduce 8 row-slots per column, for both runs.
  __shared__ float4 red[2][256];
  red[0][t] = a0;
  red[1][t] = b0;
  __syncthreads();
  if (t < 64) {
    const int which = t >> 5;   // 0 = run A, 1 = run B
    const int c     = t & 31;
    float4 sum = red[which][c];
#pragma unroll
    for (int k = 1; k < 8; ++k) acc4(sum, red[which][c + k * 32]);
    partial[((long long)b * 2 + which) * SEG_D4 + c] = sum;
  }
}

__global__ __launch_bounds__(256) void seg_finish_kernel(
    const float4* __restrict__ partial,
    const int* __restrict__ lengths,
    float4* __restrict__ out) {
  const int s    = blockIdx.x;
  const int slot = threadIdx.x >> 5;   // 0..7
  const int c    = threadIdx.x & 31;   // float4 column

  long long pre = 0;
  for (int i = 0; i < s; ++i) pre += lengths[i];
  const long long len = lengths[s];
  const long long end = pre + len;

  // Chunks whose A-run lies in segment s: pre <= b*CROWS < end.
  const int bA_lo = (int)((pre + CROWS - 1) / CROWS);
  const int bA_hi = (int)((end - 1) / CROWS);

  float4 sum = make_float4(0.f, 0.f, 0.f, 0.f);
  for (int b = bA_lo + slot; b <= bA_hi; b += 8)
    acc4(sum, partial[((long long)b * 2) * SEG_D4 + c]);

  // The straddling chunk (if the boundary is interior to it) holds s's head
  // rows in its B-slot. Added once, by slot 0.
  if (slot == 0 && (pre % CROWS) != 0) {
    const int bx = (int)(pre / CROWS);
    acc4(sum, partial[((long long)bx * 2 + 1) * SEG_D4 + c]);
  }

  __shared__ float4 red[256];
  red[threadIdx.x] = sum;
  __syncthreads();
  if (threadIdx.x < 32) {
    float4 tt = red[threadIdx.x];
#pragma unroll
    for (int k = 1; k < 8; ++k) acc4(tt, red[threadIdx.x + k * 32]);
    const float inv = 0.5f / (float)len;   // DIAG: two passes -> /(2*len)
    tt.x *= inv; tt.y *= inv; tt.z *= inv; tt.w *= inv;
    out[s * SEG_D4 + threadIdx.x] = tt;
  }
}

extern "C" void kernel_launch(void* const* d_in, const int* in_sizes, int n_in,
                              void* d_out, int out_size, void* d_ws, size_t ws_size,
                              hipStream_t stream) {
  const float* x       = (const float*)d_in[0];
  // d_in[1] = segment_ids (int32) — unused; segments contiguous, lengths suffice.
  const int*   lengths = (const int*)d_in[2];
  float*       out     = (float*)d_out;

  // lengths is int32[16]: in_sizes[2]==16 -> element counts, ==64 -> bytes.
  const bool sizes_in_bytes = (in_sizes[2] >= 64);
  const long long denom = sizes_in_bytes ? (long long)SEG_D * 4 : (long long)SEG_D;
  const int nrows = (int)((long long)in_sizes[0] / denom);
  const int T     = (nrows + CROWS - 1) / CROWS;   // 2048 for N=1M

  float4* partial = (float4*)d_ws;   // needs T*2*512 B = 2 MiB << ws_size

  seg_partial_kernel<<<T, 256, 0, stream>>>(
      (const float4*)x, lengths, partial, nrows);
  seg_finish_kernel<<<NSEG, 256, 0, stream>>>(
      partial, lengths, (float4*)out);
}

// Round 6
// 681.373 us; speedup vs baseline: 1.0993x; 1.0993x over previous
//
#include <hip/hip_runtime.h>

// Segment mean: x [N, D=128] fp32, B=16 contiguous segments (lengths[16]).
// out [16,128] fp32 = per-segment column means.
//
// v5 == v3c (reverting the v4 double-read diagnostic; that round measured the
// marginal cost of a full extra read pass at +69 µs, proving phase 1 runs at
// ~6 TB/s ≈ the HBM floor — see session journal R5).
//
// Structure: load-balanced phase 1 — every block reduces an identical
// CROWS-row chunk of the GLOBAL row space (x is contiguous across segments).
// Min segment length >> CROWS, so a chunk crosses at most ONE segment
// boundary: each block emits two partials (run A = rows before the boundary,
// run B = after; B is zeros when no boundary). Phase 2 derives
// entry->segment ownership from prefix sums of lengths — no tags, no atomics.

#define SEG_D   128
#define SEG_D4  32    // 128 floats = 32 float4
#define NSEG    16
#define CROWS   512   // rows per chunk; chunk = 256 KiB

__device__ __forceinline__ void acc4(float4& a, const float4 v) {
  a.x += v.x; a.y += v.y; a.z += v.z; a.w += v.w;
}

__global__ __launch_bounds__(256) void seg_partial_kernel(
    const float4* __restrict__ x4,
    const int* __restrict__ lengths,
    float4* __restrict__ partial,   // [T][2][SEG_D4]
    int nrows) {
  const int b = blockIdx.x;
  const int t = threadIdx.x;
  const long long row_lo = (long long)b * CROWS;
  long long row_hi = row_lo + CROWS;
  if (row_hi > nrows) row_hi = nrows;

  // Find end row of the segment containing row_lo.
  long long pre = 0, endA = 0;
  for (int i = 0; i < NSEG; ++i) {
    const long long l = lengths[i];
    if (pre + l > row_lo) { endA = pre + l; break; }
    pre += l;
  }
  const long long split = endA < row_hi ? endA : row_hi;

  const float4* __restrict__ base = x4 + row_lo * SEG_D4;
  const int nf  = (int)((row_hi - row_lo) * SEG_D4);   // <= CROWS*32 = 16384
  const int sp4 = (int)((split - row_lo) * SEG_D4);

  float4 a0 = make_float4(0.f, 0.f, 0.f, 0.f);
  float4 a1 = a0, a2 = a0, a3 = a0;           // run A accumulators
  float4 b0 = a0, b1 = a0, b2 = a0, b3 = a0;  // run B accumulators

  // 4 independent 1 KiB wave-loads in flight per iteration; thread's float4
  // column (t & 31) is invariant (strides are multiples of 32).
  int i = t;
  for (; i + 768 < nf; i += 1024) {
    const float4 v0 = base[i];
    const float4 v1 = base[i + 256];
    const float4 v2 = base[i + 512];
    const float4 v3 = base[i + 768];
    if (i       < sp4) acc4(a0, v0); else acc4(b0, v0);
    if (i + 256 < sp4) acc4(a1, v1); else acc4(b1, v1);
    if (i + 512 < sp4) acc4(a2, v2); else acc4(b2, v2);
    if (i + 768 < sp4) acc4(a3, v3); else acc4(b3, v3);
  }
  for (; i < nf; i += 256) {
    const float4 v = base[i];
    if (i < sp4) acc4(a0, v); else acc4(b0, v);
  }
  acc4(a0, a1); acc4(a2, a3); acc4(a0, a2);
  acc4(b0, b1); acc4(b2, b3); acc4(b0, b2);

  // Reduce 8 row-slots per column, for both runs.
  __shared__ float4 red[2][256];
  red[0][t] = a0;
  red[1][t] = b0;
  __syncthreads();
  if (t < 64) {
    const int which = t >> 5;   // 0 = run A, 1 = run B
    const int c     = t & 31;
    float4 sum = red[which][c];
#pragma unroll
    for (int k = 1; k < 8; ++k) acc4(sum, red[which][c + k * 32]);
    partial[((long long)b * 2 + which) * SEG_D4 + c] = sum;
  }
}

__global__ __launch_bounds__(256) void seg_finish_kernel(
    const float4* __restrict__ partial,
    const int* __restrict__ lengths,
    float4* __restrict__ out) {
  const int s    = blockIdx.x;
  const int slot = threadIdx.x >> 5;   // 0..7
  const int c    = threadIdx.x & 31;   // float4 column

  long long pre = 0;
  for (int i = 0; i < s; ++i) pre += lengths[i];
  const long long len = lengths[s];
  const long long end = pre + len;

  // Chunks whose A-run lies in segment s: pre <= b*CROWS < end.
  const int bA_lo = (int)((pre + CROWS - 1) / CROWS);
  const int bA_hi = (int)((end - 1) / CROWS);

  float4 sum = make_float4(0.f, 0.f, 0.f, 0.f);
  for (int b = bA_lo + slot; b <= bA_hi; b += 8)
    acc4(sum, partial[((long long)b * 2) * SEG_D4 + c]);

  // The straddling chunk (if the boundary is interior to it) holds s's head
  // rows in its B-slot. Added once, by slot 0.
  if (slot == 0 && (pre % CROWS) != 0) {
    const int bx = (int)(pre / CROWS);
    acc4(sum, partial[((long long)bx * 2 + 1) * SEG_D4 + c]);
  }

  __shared__ float4 red[256];
  red[threadIdx.x] = sum;
  __syncthreads();
  if (threadIdx.x < 32) {
    float4 tt = red[threadIdx.x];
#pragma unroll
    for (int k = 1; k < 8; ++k) acc4(tt, red[threadIdx.x + k * 32]);
    const float inv = 1.0f / (float)len;
    tt.x *= inv; tt.y *= inv; tt.z *= inv; tt.w *= inv;
    out[s * SEG_D4 + threadIdx.x] = tt;
  }
}

extern "C" void kernel_launch(void* const* d_in, const int* in_sizes, int n_in,
                              void* d_out, int out_size, void* d_ws, size_t ws_size,
                              hipStream_t stream) {
  const float* x       = (const float*)d_in[0];
  // d_in[1] = segment_ids (int32) — unused; segments contiguous, lengths suffice.
  const int*   lengths = (const int*)d_in[2];
  float*       out     = (float*)d_out;

  // lengths is int32[16]: in_sizes[2]==16 -> element counts, ==64 -> bytes.
  const bool sizes_in_bytes = (in_sizes[2] >= 64);
  const long long denom = sizes_in_bytes ? (long long)SEG_D * 4 : (long long)SEG_D;
  const int nrows = (int)((long long)in_sizes[0] / denom);
  const int T     = (nrows + CROWS - 1) / CROWS;   // 2048 for N=1M

  float4* partial = (float4*)d_ws;   // needs T*2*512 B = 2 MiB << ws_size

  seg_partial_kernel<<<T, 256, 0, stream>>>(
      (const float4*)x, lengths, partial, nrows);
  seg_finish_kernel<<<NSEG, 256, 0, stream>>>(
      partial, lengths, (float4*)out);
}